// Round 1
// baseline (297.625 us; speedup 1.0000x reference)
//
#include <hip/hip_runtime.h>
#include <hip/hip_bf16.h>

#define N_NODES 25000
#define N_EDGES 250000
#define N_TOT   275000   // edges + self loops
#define FDIM    256      // HEADS*HID
#define NB_SCAN 98       // ceil(N_NODES/256)

// ---------------- init: zero z and deg ----------------
__global__ void k_init(float* __restrict__ z, int* __restrict__ deg) {
    int i = blockIdx.x * 256 + threadIdx.x;
    if (i < 2 * N_NODES) z[i] = 0.f;
    if (i < N_NODES) deg[i] = 0;
}

// ---------------- GEMM: h[n][j] = sum_k x[n][k] * W[j][k] ----------------
// 64x64 output tile per block, K-chunks of 64, k-major LDS layout.
__global__ __launch_bounds__(256) void k_gemm(const float* __restrict__ x,
                                              const float* __restrict__ W,
                                              float* __restrict__ h) {
    __shared__ float xs[64 * 64];   // xs[kl*64 + row] = x[m0+row][kc+kl]
    __shared__ float ws[64 * 64];   // ws[kl*64 + col] = W[j0+col][kc+kl]
    const int m0 = blockIdx.x * 64;
    const int j0 = blockIdx.y * 64;
    const int t  = threadIdx.x;
    const int tx = t & 15, ty = t >> 4;
    const int lrow = t & 63;        // staging row (lane id)
    const int lq   = t >> 6;        // 0..3
    float acc[4][4] = {{0.f}};

    for (int kc = 0; kc < 256; kc += 64) {
        __syncthreads();
        #pragma unroll
        for (int i = 0; i < 4; ++i) {
            int kq = lq + 4 * i;            // 0..15
            int gk = kc + kq * 4;
            int node = m0 + lrow;
            float4 v = make_float4(0.f, 0.f, 0.f, 0.f);
            if (node < N_NODES) v = *reinterpret_cast<const float4*>(x + node * 256 + gk);
            xs[(kq * 4 + 0) * 64 + lrow] = v.x;
            xs[(kq * 4 + 1) * 64 + lrow] = v.y;
            xs[(kq * 4 + 2) * 64 + lrow] = v.z;
            xs[(kq * 4 + 3) * 64 + lrow] = v.w;
            float4 wv = *reinterpret_cast<const float4*>(W + (j0 + lrow) * 256 + gk);
            ws[(kq * 4 + 0) * 64 + lrow] = wv.x;
            ws[(kq * 4 + 1) * 64 + lrow] = wv.y;
            ws[(kq * 4 + 2) * 64 + lrow] = wv.z;
            ws[(kq * 4 + 3) * 64 + lrow] = wv.w;
        }
        __syncthreads();
        #pragma unroll 16
        for (int k = 0; k < 64; ++k) {
            const float4 xv = *reinterpret_cast<const float4*>(xs + k * 64 + ty * 4);
            const float4 wv = *reinterpret_cast<const float4*>(ws + k * 64 + tx * 4);
            acc[0][0] += xv.x * wv.x; acc[0][1] += xv.x * wv.y; acc[0][2] += xv.x * wv.z; acc[0][3] += xv.x * wv.w;
            acc[1][0] += xv.y * wv.x; acc[1][1] += xv.y * wv.y; acc[1][2] += xv.y * wv.z; acc[1][3] += xv.y * wv.w;
            acc[2][0] += xv.z * wv.x; acc[2][1] += xv.z * wv.y; acc[2][2] += xv.z * wv.z; acc[2][3] += xv.z * wv.w;
            acc[3][0] += xv.w * wv.x; acc[3][1] += xv.w * wv.y; acc[3][2] += xv.w * wv.z; acc[3][3] += xv.w * wv.w;
        }
    }
    #pragma unroll
    for (int r = 0; r < 4; ++r) {
        int node = m0 + ty * 4 + r;
        if (node < N_NODES) {
            float4 o = make_float4(acc[r][0], acc[r][1], acc[r][2], acc[r][3]);
            *reinterpret_cast<float4*>(h + node * FDIM + j0 + tx * 4) = o;
        }
    }
}

// ---------------- per-(node,head) attention projections ----------------
__global__ __launch_bounds__(256) void k_att(const float* __restrict__ h,
                                             const float* __restrict__ att_src,
                                             const float* __restrict__ att_dst,
                                             float* __restrict__ a_src,
                                             float* __restrict__ a_dst) {
    int gt   = blockIdx.x * 256 + threadIdx.x;
    int wid  = gt >> 6;                  // (node,head) index, 0..49999
    int lane = threadIdx.x & 63;
    int n  = wid >> 1;
    int hd = wid & 1;
    const float* hp  = h + n * FDIM + hd * 128;
    const float* asp = att_src + hd * 128;
    const float* adp = att_dst + hd * 128;
    float s = hp[lane] * asp[lane] + hp[lane + 64] * asp[lane + 64];
    float d = hp[lane] * adp[lane] + hp[lane + 64] * adp[lane + 64];
    #pragma unroll
    for (int o = 32; o > 0; o >>= 1) {
        s += __shfl_down(s, o);
        d += __shfl_down(d, o);
    }
    if (lane == 0) { a_src[wid] = s; a_dst[wid] = d; }
}

// ---------------- edge logits: ex = exp(leaky(a_s+a_d)), z += ex, deg++ ---
__global__ void k_edge_logits(const int* __restrict__ ei,
                              const float* __restrict__ a_src,
                              const float* __restrict__ a_dst,
                              float* __restrict__ ex,
                              float* __restrict__ z,
                              int* __restrict__ deg) {
    int i = blockIdx.x * 256 + threadIdx.x;
    if (i >= N_TOT) return;
    int src, dst;
    if (i < N_EDGES) { src = ei[i]; dst = ei[N_EDGES + i]; }
    else             { src = dst = i - N_EDGES; }
    #pragma unroll
    for (int hd = 0; hd < 2; ++hd) {
        float v = a_src[src * 2 + hd] + a_dst[dst * 2 + hd];
        v = v > 0.f ? v : 0.2f * v;
        float e = expf(v);       // softmax is shift-invariant; |v| small -> no max pass
        ex[i * 2 + hd] = e;
        atomicAdd(&z[dst * 2 + hd], e);
    }
    atomicAdd(&deg[dst], 1);
}

// ---------------- hierarchical exclusive scan of deg -> offs ----------------
__global__ __launch_bounds__(256) void k_scan1(const int* __restrict__ deg,
                                               int* __restrict__ offs,
                                               int* __restrict__ bsum) {
    __shared__ int sh[256];
    int b = blockIdx.x, t = threadIdx.x;
    int i = b * 256 + t;
    int v = (i < N_NODES) ? deg[i] : 0;
    sh[t] = v;
    __syncthreads();
    #pragma unroll
    for (int o = 1; o < 256; o <<= 1) {
        int u = (t >= o) ? sh[t - o] : 0;
        __syncthreads();
        sh[t] += u;
        __syncthreads();
    }
    int incl = sh[t];
    if (i < N_NODES) offs[i] = incl - v;
    if (t == 255) bsum[b] = incl;
}

__global__ __launch_bounds__(128) void k_scan2(int* __restrict__ bsum) {
    __shared__ int sh[128];
    int t = threadIdx.x;
    int v = (t < NB_SCAN) ? bsum[t] : 0;
    sh[t] = v;
    __syncthreads();
    #pragma unroll
    for (int o = 1; o < 128; o <<= 1) {
        int u = (t >= o) ? sh[t - o] : 0;
        __syncthreads();
        sh[t] += u;
        __syncthreads();
    }
    if (t < NB_SCAN) bsum[t] = sh[t] - v;   // exclusive
}

__global__ __launch_bounds__(256) void k_scan3(int* __restrict__ offs,
                                               const int* __restrict__ bsum,
                                               int* __restrict__ cursor) {
    int i = blockIdx.x * 256 + threadIdx.x;
    if (i < N_NODES) {
        int o = offs[i] + bsum[i >> 8];
        offs[i]   = o;
        cursor[i] = o;
    }
}

// ---------------- CSR fill: csr[pos] = {src, ex0, ex1} ----------------
__global__ void k_csr_fill(const int* __restrict__ ei,
                           const float* __restrict__ ex,
                           int* __restrict__ cursor,
                           float4* __restrict__ csr) {
    int i = blockIdx.x * 256 + threadIdx.x;
    if (i >= N_TOT) return;
    int src, dst;
    if (i < N_EDGES) { src = ei[i]; dst = ei[N_EDGES + i]; }
    else             { src = dst = i - N_EDGES; }
    int pos = atomicAdd(&cursor[dst], 1);
    float4 r;
    r.x = __int_as_float(src);
    r.y = ex[i * 2 + 0];
    r.z = ex[i * 2 + 1];
    r.w = 0.f;
    csr[pos] = r;
}

// ---------------- per-node aggregation + fused h2 + fc1 projections -------
__global__ __launch_bounds__(256) void k_node_aggregate(const float4* __restrict__ csr,
                                                        const int* __restrict__ offs,
                                                        const int* __restrict__ deg,
                                                        const float* __restrict__ z,
                                                        const float* __restrict__ h,
                                                        const float* __restrict__ bias,
                                                        const float* __restrict__ fc1_w,
                                                        float* __restrict__ p_src,
                                                        float* __restrict__ p_dst) {
    __shared__ float red[4][6];
    int n = blockIdx.x;
    int t = threadIdx.x;
    int hd = t >> 7;
    int s = offs[n];
    int e = s + deg[n];
    float acc = 0.f;
    for (int it = s; it < e; ++it) {
        float4 r = csr[it];
        int src = __float_as_int(r.x);
        float w = hd ? r.z : r.y;
        acc += w * h[src * FDIM + t];
    }
    float h2 = acc / z[n * 2 + hd] + bias[t];
    h2 = h2 > 0.f ? h2 : 0.01f * h2;
    // 6 dot products: p_src[k] = sum_t fc1_w[k*512+t]*h2 ; p_dst[k] = sum_t fc1_w[k*512+256+t]*h2
    float v0 = fc1_w[0 * 512 + t] * h2;
    float v1 = fc1_w[1 * 512 + t] * h2;
    float v2 = fc1_w[2 * 512 + t] * h2;
    float v3 = fc1_w[0 * 512 + 256 + t] * h2;
    float v4 = fc1_w[1 * 512 + 256 + t] * h2;
    float v5 = fc1_w[2 * 512 + 256 + t] * h2;
    #pragma unroll
    for (int o = 32; o > 0; o >>= 1) {
        v0 += __shfl_down(v0, o); v1 += __shfl_down(v1, o); v2 += __shfl_down(v2, o);
        v3 += __shfl_down(v3, o); v4 += __shfl_down(v4, o); v5 += __shfl_down(v5, o);
    }
    int lane = t & 63, w = t >> 6;
    if (lane == 0) {
        red[w][0] = v0; red[w][1] = v1; red[w][2] = v2;
        red[w][3] = v3; red[w][4] = v4; red[w][5] = v5;
    }
    __syncthreads();
    if (t < 6) {
        float sum = red[0][t] + red[1][t] + red[2][t] + red[3][t];
        if (t < 3) p_src[n * 3 + t] = sum;
        else       p_dst[n * 3 + (t - 3)] = sum;
    }
}

// ---------------- final per-edge output ----------------
__global__ void k_edge_out(const int* __restrict__ ei,
                           const float* __restrict__ p_src,
                           const float* __restrict__ p_dst,
                           const float* __restrict__ fc1_b,
                           float* __restrict__ out) {
    int i = blockIdx.x * 256 + threadIdx.x;
    if (i >= N_EDGES) return;
    int s = ei[i], d = ei[N_EDGES + i];
    out[i * 3 + 0] = p_src[s * 3 + 0] + p_dst[d * 3 + 0] + fc1_b[0];
    out[i * 3 + 1] = p_src[s * 3 + 1] + p_dst[d * 3 + 1] + fc1_b[1];
    out[i * 3 + 2] = p_src[s * 3 + 2] + p_dst[d * 3 + 2] + fc1_b[2];
}

extern "C" void kernel_launch(void* const* d_in, const int* in_sizes, int n_in,
                              void* d_out, int out_size, void* d_ws, size_t ws_size,
                              hipStream_t stream) {
    const float* x       = (const float*)d_in[0];
    const int*   ei      = (const int*)d_in[1];
    const float* W       = (const float*)d_in[2];
    const float* att_src = (const float*)d_in[3];
    const float* att_dst = (const float*)d_in[4];
    const float* bias    = (const float*)d_in[5];
    const float* fc1_w   = (const float*)d_in[6];
    const float* fc1_b   = (const float*)d_in[7];
    float* out = (float*)d_out;

    // workspace layout (csr first for 16B alignment)
    float4* csr  = (float4*)d_ws;                       // 275000 * 16B
    float* h     = (float*)(csr + N_TOT);               // 25000*256
    float* ex    = h + N_NODES * FDIM;                  // 275000*2
    float* z     = ex + N_TOT * 2;                      // 50000
    float* a_src = z + 2 * N_NODES;                     // 50000
    float* a_dst = a_src + 2 * N_NODES;                 // 50000
    float* p_src = a_dst + 2 * N_NODES;                 // 75000
    float* p_dst = p_src + 3 * N_NODES;                 // 75000
    int* deg     = (int*)(p_dst + 3 * N_NODES);         // 25000
    int* offs    = deg + N_NODES;                       // 25000
    int* cursor  = offs + N_NODES;                      // 25000
    int* bsum    = cursor + N_NODES;                    // 128

    k_init<<<(2 * N_NODES + 255) / 256, 256, 0, stream>>>(z, deg);
    k_gemm<<<dim3((N_NODES + 63) / 64, FDIM / 64), 256, 0, stream>>>(x, W, h);
    k_att<<<(N_NODES * 2 * 64) / 256, 256, 0, stream>>>(h, att_src, att_dst, a_src, a_dst);
    k_edge_logits<<<(N_TOT + 255) / 256, 256, 0, stream>>>(ei, a_src, a_dst, ex, z, deg);
    k_scan1<<<NB_SCAN, 256, 0, stream>>>(deg, offs, bsum);
    k_scan2<<<1, 128, 0, stream>>>(bsum);
    k_scan3<<<NB_SCAN, 256, 0, stream>>>(offs, bsum, cursor);
    k_csr_fill<<<(N_TOT + 255) / 256, 256, 0, stream>>>(ei, ex, cursor, csr);
    k_node_aggregate<<<N_NODES, 256, 0, stream>>>(csr, offs, deg, z, h, bias, fc1_w, p_src, p_dst);
    k_edge_out<<<(N_EDGES + 255) / 256, 256, 0, stream>>>(ei, p_src, p_dst, fc1_b, out);
}

// Round 2
// 229.536 us; speedup vs baseline: 1.2966x; 1.2966x over previous
//
#include <hip/hip_runtime.h>
#include <hip/hip_bf16.h>

#define N_NODES 25000
#define N_EDGES 250000
#define N_TOT   275000   // edges + self loops
#define FDIM    256      // HEADS*HID
#define NB_SCAN 98       // ceil(N_NODES/256)

// ---------------- init: zero a_src/a_dst, deg = 1 (self loop) ----------------
__global__ void k_init(float* __restrict__ a_src, float* __restrict__ a_dst,
                       int* __restrict__ deg) {
    int i = blockIdx.x * 256 + threadIdx.x;
    if (i < 2 * N_NODES) { a_src[i] = 0.f; a_dst[i] = 0.f; }
    if (i < N_NODES) deg[i] = 1;
}

// ---------------- degree count (edges only; self loop pre-counted) -----------
__global__ void k_deg(const int* __restrict__ ei, int* __restrict__ deg) {
    int i = blockIdx.x * 256 + threadIdx.x;
    if (i < N_EDGES) atomicAdd(&deg[ei[N_EDGES + i]], 1);
}

// ---------------- GEMM: h[n][j] = sum_k x[n][k]*W[j][k], bf16 store, fused att
__global__ __launch_bounds__(256) void k_gemm(const float* __restrict__ x,
                                              const float* __restrict__ W,
                                              const float* __restrict__ att_src,
                                              const float* __restrict__ att_dst,
                                              __hip_bfloat16* __restrict__ hb,
                                              float* __restrict__ a_src,
                                              float* __restrict__ a_dst) {
    __shared__ float xs[64 * 64];   // xs[kl*64 + row] = x[m0+row][kc+kl]
    __shared__ float ws[64 * 64];   // ws[kl*64 + col] = W[j0+col][kc+kl]
    const int m0 = blockIdx.x * 64;
    const int j0 = blockIdx.y * 64;
    const int t  = threadIdx.x;
    const int tx = t & 15, ty = t >> 4;
    const int lrow = t & 63;
    const int lq   = t >> 6;
    float acc[4][4] = {{0.f}};

    for (int kc = 0; kc < 256; kc += 64) {
        __syncthreads();
        #pragma unroll
        for (int i = 0; i < 4; ++i) {
            int kq = lq + 4 * i;
            int gk = kc + kq * 4;
            int node = m0 + lrow;
            float4 v = make_float4(0.f, 0.f, 0.f, 0.f);
            if (node < N_NODES) v = *reinterpret_cast<const float4*>(x + node * 256 + gk);
            xs[(kq * 4 + 0) * 64 + lrow] = v.x;
            xs[(kq * 4 + 1) * 64 + lrow] = v.y;
            xs[(kq * 4 + 2) * 64 + lrow] = v.z;
            xs[(kq * 4 + 3) * 64 + lrow] = v.w;
            float4 wv = *reinterpret_cast<const float4*>(W + (j0 + lrow) * 256 + gk);
            ws[(kq * 4 + 0) * 64 + lrow] = wv.x;
            ws[(kq * 4 + 1) * 64 + lrow] = wv.y;
            ws[(kq * 4 + 2) * 64 + lrow] = wv.z;
            ws[(kq * 4 + 3) * 64 + lrow] = wv.w;
        }
        __syncthreads();
        #pragma unroll 16
        for (int k = 0; k < 64; ++k) {
            const float4 xv = *reinterpret_cast<const float4*>(xs + k * 64 + ty * 4);
            const float4 wv = *reinterpret_cast<const float4*>(ws + k * 64 + tx * 4);
            acc[0][0] += xv.x * wv.x; acc[0][1] += xv.x * wv.y; acc[0][2] += xv.x * wv.z; acc[0][3] += xv.x * wv.w;
            acc[1][0] += xv.y * wv.x; acc[1][1] += xv.y * wv.y; acc[1][2] += xv.y * wv.z; acc[1][3] += xv.y * wv.w;
            acc[2][0] += xv.z * wv.x; acc[2][1] += xv.z * wv.y; acc[2][2] += xv.z * wv.z; acc[2][3] += xv.z * wv.w;
            acc[3][0] += xv.w * wv.x; acc[3][1] += xv.w * wv.y; acc[3][2] += xv.w * wv.z; acc[3][3] += xv.w * wv.w;
        }
    }
    // store bf16 h tile
    #pragma unroll
    for (int r = 0; r < 4; ++r) {
        int node = m0 + ty * 4 + r;
        if (node < N_NODES) {
            __hip_bfloat16 tmp[4];
            tmp[0] = __float2bfloat16(acc[r][0]);
            tmp[1] = __float2bfloat16(acc[r][1]);
            tmp[2] = __float2bfloat16(acc[r][2]);
            tmp[3] = __float2bfloat16(acc[r][3]);
            *reinterpret_cast<ushort4*>(hb + node * FDIM + j0 + tx * 4) =
                *reinterpret_cast<const ushort4*>(tmp);
        }
    }
    // fused attention partial dots (cols j0..j0+63 are within one head)
    const int hd0 = j0 >> 7;
    float as_[4], ad_[4];
    #pragma unroll
    for (int c = 0; c < 4; ++c) {
        as_[c] = att_src[j0 + tx * 4 + c];   // att flat index == global col
        ad_[c] = att_dst[j0 + tx * 4 + c];
    }
    #pragma unroll
    for (int r = 0; r < 4; ++r) {
        float ps = acc[r][0] * as_[0] + acc[r][1] * as_[1] + acc[r][2] * as_[2] + acc[r][3] * as_[3];
        float pd = acc[r][0] * ad_[0] + acc[r][1] * ad_[1] + acc[r][2] * ad_[2] + acc[r][3] * ad_[3];
        #pragma unroll
        for (int o = 8; o > 0; o >>= 1) {     // reduce over tx (aligned 16-lane groups)
            ps += __shfl_down(ps, o);
            pd += __shfl_down(pd, o);
        }
        if (tx == 0) {
            int node = m0 + ty * 4 + r;
            if (node < N_NODES) {
                atomicAdd(&a_src[node * 2 + hd0], ps);
                atomicAdd(&a_dst[node * 2 + hd0], pd);
            }
        }
    }
}

// ---------------- hierarchical exclusive scan of deg -> offs ----------------
__global__ __launch_bounds__(256) void k_scan1(const int* __restrict__ deg,
                                               int* __restrict__ offs,
                                               int* __restrict__ bsum) {
    __shared__ int sh[256];
    int b = blockIdx.x, t = threadIdx.x;
    int i = b * 256 + t;
    int v = (i < N_NODES) ? deg[i] : 0;
    sh[t] = v;
    __syncthreads();
    #pragma unroll
    for (int o = 1; o < 256; o <<= 1) {
        int u = (t >= o) ? sh[t - o] : 0;
        __syncthreads();
        sh[t] += u;
        __syncthreads();
    }
    int incl = sh[t];
    if (i < N_NODES) offs[i] = incl - v;
    if (t == 255) bsum[b] = incl;
}

__global__ __launch_bounds__(128) void k_scan2(int* __restrict__ bsum) {
    __shared__ int sh[128];
    int t = threadIdx.x;
    int v = (t < NB_SCAN) ? bsum[t] : 0;
    sh[t] = v;
    __syncthreads();
    #pragma unroll
    for (int o = 1; o < 128; o <<= 1) {
        int u = (t >= o) ? sh[t - o] : 0;
        __syncthreads();
        sh[t] += u;
        __syncthreads();
    }
    if (t < NB_SCAN) bsum[t] = sh[t] - v;   // exclusive
}

__global__ __launch_bounds__(256) void k_scan3(int* __restrict__ offs,
                                               const int* __restrict__ bsum,
                                               int* __restrict__ cursor) {
    int i = blockIdx.x * 256 + threadIdx.x;
    if (i < N_NODES) {
        int o = offs[i] + bsum[i >> 8];
        offs[i]   = o;
        cursor[i] = o;
    }
}

// ------- CSR fill: compute ex inline, scatter {src, ex0, ex1} -------
__global__ void k_csr_fill(const int* __restrict__ ei,
                           const float* __restrict__ a_src,
                           const float* __restrict__ a_dst,
                           int* __restrict__ cursor,
                           float4* __restrict__ csr) {
    int i = blockIdx.x * 256 + threadIdx.x;
    if (i >= N_TOT) return;
    int src, dst;
    if (i < N_EDGES) { src = ei[i]; dst = ei[N_EDGES + i]; }
    else             { src = dst = i - N_EDGES; }
    float v0 = a_src[src * 2 + 0] + a_dst[dst * 2 + 0];
    float v1 = a_src[src * 2 + 1] + a_dst[dst * 2 + 1];
    v0 = v0 > 0.f ? v0 : 0.2f * v0;
    v1 = v1 > 0.f ? v1 : 0.2f * v1;
    int pos = atomicAdd(&cursor[dst], 1);
    float4 r;
    r.x = __int_as_float(src);
    r.y = expf(v0);          // softmax shift-invariant; |v| small -> no max pass
    r.z = expf(v1);
    r.w = 0.f;
    csr[pos] = r;
}

// ------- per-node aggregation (bf16 h gather, 4x unrolled) + fused fc1 -------
__global__ __launch_bounds__(256) void k_node_aggregate(const float4* __restrict__ csr,
                                                        const int* __restrict__ offs,
                                                        const int* __restrict__ deg,
                                                        const __hip_bfloat16* __restrict__ hb,
                                                        const float* __restrict__ bias,
                                                        const float* __restrict__ fc1_w,
                                                        const float* __restrict__ fc1_b,
                                                        float* __restrict__ p_src,
                                                        float* __restrict__ p_dst) {
    __shared__ float red[4][6];
    const int n = blockIdx.x;
    const int t = threadIdx.x;
    const int hd = t >> 7;
    const int s = offs[n];
    const int e = s + deg[n];
    float acc0 = 0.f, acc1 = 0.f, acc2 = 0.f, acc3 = 0.f;
    float zs0 = 0.f, zs1 = 0.f;
    int it = s;
    for (; it + 4 <= e; it += 4) {
        float4 r0 = csr[it], r1 = csr[it + 1], r2 = csr[it + 2], r3 = csr[it + 3];
        int s0 = __float_as_int(r0.x), s1 = __float_as_int(r1.x);
        int s2 = __float_as_int(r2.x), s3 = __float_as_int(r3.x);
        float w0 = hd ? r0.z : r0.y;
        float w1 = hd ? r1.z : r1.y;
        float w2 = hd ? r2.z : r2.y;
        float w3 = hd ? r3.z : r3.y;
        acc0 += w0 * __bfloat162float(hb[s0 * FDIM + t]);
        acc1 += w1 * __bfloat162float(hb[s1 * FDIM + t]);
        acc2 += w2 * __bfloat162float(hb[s2 * FDIM + t]);
        acc3 += w3 * __bfloat162float(hb[s3 * FDIM + t]);
        zs0 += w0 + w1;
        zs1 += w2 + w3;
    }
    for (; it < e; ++it) {
        float4 r = csr[it];
        int sr = __float_as_int(r.x);
        float w = hd ? r.z : r.y;
        acc0 += w * __bfloat162float(hb[sr * FDIM + t]);
        zs0 += w;
    }
    float acc = (acc0 + acc1) + (acc2 + acc3);
    float zs  = zs0 + zs1;
    float h2 = acc / zs + bias[t];
    h2 = h2 > 0.f ? h2 : 0.01f * h2;
    // 6 dots: p_src[k] = sum_t fc1_w[k*512+t]*h2 ; p_dst[k] = sum_t fc1_w[k*512+256+t]*h2
    float v0 = fc1_w[0 * 512 + t] * h2;
    float v1 = fc1_w[1 * 512 + t] * h2;
    float v2 = fc1_w[2 * 512 + t] * h2;
    float v3 = fc1_w[0 * 512 + 256 + t] * h2;
    float v4 = fc1_w[1 * 512 + 256 + t] * h2;
    float v5 = fc1_w[2 * 512 + 256 + t] * h2;
    #pragma unroll
    for (int o = 32; o > 0; o >>= 1) {
        v0 += __shfl_down(v0, o); v1 += __shfl_down(v1, o); v2 += __shfl_down(v2, o);
        v3 += __shfl_down(v3, o); v4 += __shfl_down(v4, o); v5 += __shfl_down(v5, o);
    }
    int lane = t & 63, w = t >> 6;
    if (lane == 0) {
        red[w][0] = v0; red[w][1] = v1; red[w][2] = v2;
        red[w][3] = v3; red[w][4] = v4; red[w][5] = v5;
    }
    __syncthreads();
    if (t < 6) {
        float sum = red[0][t] + red[1][t] + red[2][t] + red[3][t];
        if (t < 3) p_src[n * 3 + t] = sum + fc1_b[t];   // fold bias into p_src
        else       p_dst[n * 3 + (t - 3)] = sum;
    }
}

// ---------------- final per-edge output ----------------
__global__ void k_edge_out(const int* __restrict__ ei,
                           const float* __restrict__ p_src,
                           const float* __restrict__ p_dst,
                           float* __restrict__ out) {
    int i = blockIdx.x * 256 + threadIdx.x;
    if (i >= N_EDGES) return;
    int s = ei[i], d = ei[N_EDGES + i];
    out[i * 3 + 0] = p_src[s * 3 + 0] + p_dst[d * 3 + 0];
    out[i * 3 + 1] = p_src[s * 3 + 1] + p_dst[d * 3 + 1];
    out[i * 3 + 2] = p_src[s * 3 + 2] + p_dst[d * 3 + 2];
}

extern "C" void kernel_launch(void* const* d_in, const int* in_sizes, int n_in,
                              void* d_out, int out_size, void* d_ws, size_t ws_size,
                              hipStream_t stream) {
    const float* x       = (const float*)d_in[0];
    const int*   ei      = (const int*)d_in[1];
    const float* W       = (const float*)d_in[2];
    const float* att_src = (const float*)d_in[3];
    const float* att_dst = (const float*)d_in[4];
    const float* bias    = (const float*)d_in[5];
    const float* fc1_w   = (const float*)d_in[6];
    const float* fc1_b   = (const float*)d_in[7];
    float* out = (float*)d_out;

    // workspace layout (csr first for 16B alignment)
    float4* csr = (float4*)d_ws;                             // 275000 * 16B
    __hip_bfloat16* hb = (__hip_bfloat16*)(csr + N_TOT);     // 25000*256 bf16
    float* a_src = (float*)(hb + N_NODES * FDIM);            // 50000
    float* a_dst = a_src + 2 * N_NODES;                      // 50000
    float* p_src = a_dst + 2 * N_NODES;                      // 75000
    float* p_dst = p_src + 3 * N_NODES;                      // 75000
    int* deg     = (int*)(p_dst + 3 * N_NODES);              // 25000
    int* offs    = deg + N_NODES;                            // 25000
    int* cursor  = offs + N_NODES;                           // 25000
    int* bsum    = cursor + N_NODES;                         // 128

    k_init<<<(2 * N_NODES + 255) / 256, 256, 0, stream>>>(a_src, a_dst, deg);
    k_deg<<<(N_EDGES + 255) / 256, 256, 0, stream>>>(ei, deg);
    k_gemm<<<dim3((N_NODES + 63) / 64, FDIM / 64), 256, 0, stream>>>(
        x, W, att_src, att_dst, hb, a_src, a_dst);
    k_scan1<<<NB_SCAN, 256, 0, stream>>>(deg, offs, bsum);
    k_scan2<<<1, 128, 0, stream>>>(bsum);
    k_scan3<<<NB_SCAN, 256, 0, stream>>>(offs, bsum, cursor);
    k_csr_fill<<<(N_TOT + 255) / 256, 256, 0, stream>>>(ei, a_src, a_dst, cursor, csr);
    k_node_aggregate<<<N_NODES, 256, 0, stream>>>(csr, offs, deg, hb, bias, fc1_w, fc1_b,
                                                  p_src, p_dst);
    k_edge_out<<<(N_EDGES + 255) / 256, 256, 0, stream>>>(ei, p_src, p_dst, out);
}

// Round 3
// 191.715 us; speedup vs baseline: 1.5524x; 1.1973x over previous
//
#include <hip/hip_runtime.h>
#include <hip/hip_bf16.h>

#define N_NODES 25000
#define N_EDGES 250000
#define N_TOT   275000   // edges + self loops
#define FDIM    256      // HEADS*HID
#define NB_SCAN 98       // ceil(N_NODES/256)
#define M_PAD   25024    // 391*64 (gemm row padding)

typedef __attribute__((ext_vector_type(8))) short bf16x8;
typedef __attribute__((ext_vector_type(4))) float f32x4;

__device__ inline unsigned short f2bf(float f) {
    union { float f; unsigned u; } v; v.f = f;
    unsigned r = (v.u + 0x7FFFu + ((v.u >> 16) & 1u)) >> 16;   // RNE
    return (unsigned short)r;
}
__device__ inline float bf2f(unsigned short s) {
    union { unsigned u; float f; } v; v.u = ((unsigned)s) << 16;
    return v.f;
}

// ---------------- init: deg = 1 (self loop) ----------------
__global__ void k_init(int* __restrict__ deg) {
    int i = blockIdx.x * 256 + threadIdx.x;
    if (i < N_NODES) deg[i] = 1;
}

// ---------------- degree count (edges only) ----------------
__global__ void k_deg(const int* __restrict__ ei, int* __restrict__ deg) {
    int i = blockIdx.x * 256 + threadIdx.x;
    if (i < N_EDGES) atomicAdd(&deg[ei[N_EDGES + i]], 1);
}

// ------- MFMA GEMM: hb[n][j] = sum_k x[n][k]*W[j][k]  (bf16 in, f32 acc) -----
// BM=64, BN=256 (full), BK=64. 512 threads = 8 waves, wave = 32 rows x 64 cols.
// LDS tiles [row][64k] bf16 with XOR swizzle byte^=(row&7)<<4 (T2).
__global__ __launch_bounds__(512) void k_gemm(const float* __restrict__ x,
                                              const float* __restrict__ W,
                                              unsigned short* __restrict__ hb) {
    __shared__ char lds[40960];          // A: [0,8K) 64x64, B: [8K,40K) 256x64
    const int m0   = blockIdx.x * 64;
    const int t    = threadIdx.x;
    const int lane = t & 63;
    const int wid  = t >> 6;             // 0..7
    const int wr   = wid >> 2;           // row-group (32 rows)
    const int wc   = wid & 3;            // col-group (64 cols)
    f32x4 acc[2][4];
    #pragma unroll
    for (int mi = 0; mi < 2; ++mi)
        #pragma unroll
        for (int ni = 0; ni < 4; ++ni)
            acc[mi][ni] = (f32x4){0.f, 0.f, 0.f, 0.f};

    for (int kc = 0; kc < 256; kc += 64) {
        __syncthreads();                 // protect LDS reuse
        // stage A: 64 rows x 64 k  (1024 float4, 2 per thread)
        #pragma unroll
        for (int q = 0; q < 2; ++q) {
            int fi = q * 512 + t;
            int row = fi >> 4, ks4 = fi & 15;
            int node = m0 + row;
            f32x4 v = (f32x4){0.f, 0.f, 0.f, 0.f};
            if (node < N_NODES) v = *reinterpret_cast<const f32x4*>(x + node * 256 + kc + ks4 * 4);
            ushort4 b;
            b.x = f2bf(v.x); b.y = f2bf(v.y); b.z = f2bf(v.z); b.w = f2bf(v.w);
            int byte = (row * 128 + ks4 * 8) ^ ((row & 7) << 4);
            *reinterpret_cast<ushort4*>(lds + byte) = b;
        }
        // stage B: 256 cols x 64 k (4096 float4, 8 per thread)
        #pragma unroll
        for (int q = 0; q < 8; ++q) {
            int fi = q * 512 + t;
            int col = fi >> 4, ks4 = fi & 15;
            f32x4 v = *reinterpret_cast<const f32x4*>(W + col * 256 + kc + ks4 * 4);
            ushort4 b;
            b.x = f2bf(v.x); b.y = f2bf(v.y); b.z = f2bf(v.z); b.w = f2bf(v.w);
            int byte = 8192 + ((col * 128 + ks4 * 8) ^ ((col & 7) << 4));
            *reinterpret_cast<ushort4*>(lds + byte) = b;
        }
        __syncthreads();
        #pragma unroll
        for (int ks = 0; ks < 2; ++ks) {
            bf16x8 a[2], b[4];
            #pragma unroll
            for (int mi = 0; mi < 2; ++mi) {
                int row = wr * 32 + mi * 16 + (lane & 15);
                int byte = (row * 128 + ks * 64 + (lane >> 4) * 16) ^ ((row & 7) << 4);
                a[mi] = *reinterpret_cast<const bf16x8*>(lds + byte);
            }
            #pragma unroll
            for (int ni = 0; ni < 4; ++ni) {
                int col = wc * 64 + ni * 16 + (lane & 15);
                int byte = 8192 + ((col * 128 + ks * 64 + (lane >> 4) * 16) ^ ((col & 7) << 4));
                b[ni] = *reinterpret_cast<const bf16x8*>(lds + byte);
            }
            #pragma unroll
            for (int mi = 0; mi < 2; ++mi)
                #pragma unroll
                for (int ni = 0; ni < 4; ++ni)
                    acc[mi][ni] = __builtin_amdgcn_mfma_f32_16x16x32_bf16(
                        a[mi], b[ni], acc[mi][ni], 0, 0, 0);
        }
    }
    // epilogue: C/D layout col = lane&15, row = (lane>>4)*4 + r  (m89-verified)
    #pragma unroll
    for (int mi = 0; mi < 2; ++mi)
        #pragma unroll
        for (int r = 0; r < 4; ++r) {
            int row = m0 + wr * 32 + mi * 16 + (lane >> 4) * 4 + r;   // < M_PAD (hb padded)
            #pragma unroll
            for (int ni = 0; ni < 4; ++ni) {
                int col = wc * 64 + ni * 16 + (lane & 15);
                hb[row * 256 + col] = f2bf(acc[mi][ni][r]);
            }
        }
}

// ---------------- attention dots from bf16 h: wave per node ----------------
__global__ __launch_bounds__(256) void k_att(const unsigned short* __restrict__ hb,
                                             const float* __restrict__ att_src,
                                             const float* __restrict__ att_dst,
                                             float* __restrict__ a_src,
                                             float* __restrict__ a_dst) {
    int gt = blockIdx.x * 256 + threadIdx.x;
    int n = gt >> 6;
    int lane = gt & 63;
    if (n >= N_NODES) return;
    ushort4 hv = *reinterpret_cast<const ushort4*>(hb + n * 256 + lane * 4);
    f32x4 as = *reinterpret_cast<const f32x4*>(att_src + lane * 4);
    f32x4 ad = *reinterpret_cast<const f32x4*>(att_dst + lane * 4);
    float h0 = bf2f(hv.x), h1 = bf2f(hv.y), h2 = bf2f(hv.z), h3 = bf2f(hv.w);
    float s = h0 * as.x + h1 * as.y + h2 * as.z + h3 * as.w;
    float d = h0 * ad.x + h1 * ad.y + h2 * ad.z + h3 * ad.w;
    #pragma unroll
    for (int o = 16; o > 0; o >>= 1) {      // reduce within 32-lane halves (per head)
        s += __shfl_xor(s, o, 32);
        d += __shfl_xor(d, o, 32);
    }
    if ((lane & 31) == 0) {
        int hd = lane >> 5;
        a_src[n * 2 + hd] = s;
        a_dst[n * 2 + hd] = d;
    }
}

// ---------------- hierarchical exclusive scan of deg -> offs ----------------
__global__ __launch_bounds__(256) void k_scan1(const int* __restrict__ deg,
                                               int* __restrict__ offs,
                                               int* __restrict__ bsum) {
    __shared__ int sh[256];
    int b = blockIdx.x, t = threadIdx.x;
    int i = b * 256 + t;
    int v = (i < N_NODES) ? deg[i] : 0;
    sh[t] = v;
    __syncthreads();
    #pragma unroll
    for (int o = 1; o < 256; o <<= 1) {
        int u = (t >= o) ? sh[t - o] : 0;
        __syncthreads();
        sh[t] += u;
        __syncthreads();
    }
    int incl = sh[t];
    if (i < N_NODES) offs[i] = incl - v;
    if (t == 255) bsum[b] = incl;
}

__global__ __launch_bounds__(128) void k_scan2(int* __restrict__ bsum) {
    __shared__ int sh[128];
    int t = threadIdx.x;
    int v = (t < NB_SCAN) ? bsum[t] : 0;
    sh[t] = v;
    __syncthreads();
    #pragma unroll
    for (int o = 1; o < 128; o <<= 1) {
        int u = (t >= o) ? sh[t - o] : 0;
        __syncthreads();
        sh[t] += u;
        __syncthreads();
    }
    if (t < NB_SCAN) bsum[t] = sh[t] - v;   // exclusive
}

__global__ __launch_bounds__(256) void k_scan3(int* __restrict__ offs,
                                               const int* __restrict__ bsum,
                                               int* __restrict__ cursor) {
    int i = blockIdx.x * 256 + threadIdx.x;
    if (i < N_NODES) {
        int o = offs[i] + bsum[i >> 8];
        offs[i]   = o;
        cursor[i] = o;
    }
}

// ------- CSR fill: compute ex inline, scatter {src, ex0, ex1} -------
__global__ void k_csr_fill(const int* __restrict__ ei,
                           const float* __restrict__ a_src,
                           const float* __restrict__ a_dst,
                           int* __restrict__ cursor,
                           float4* __restrict__ csr) {
    int i = blockIdx.x * 256 + threadIdx.x;
    if (i >= N_TOT) return;
    int src, dst;
    if (i < N_EDGES) { src = ei[i]; dst = ei[N_EDGES + i]; }
    else             { src = dst = i - N_EDGES; }
    float v0 = a_src[src * 2 + 0] + a_dst[dst * 2 + 0];
    float v1 = a_src[src * 2 + 1] + a_dst[dst * 2 + 1];
    v0 = v0 > 0.f ? v0 : 0.2f * v0;
    v1 = v1 > 0.f ? v1 : 0.2f * v1;
    int pos = atomicAdd(&cursor[dst], 1);
    float4 r;
    r.x = __int_as_float(src);
    r.y = expf(v0);          // softmax shift-invariant; |v| small -> no max pass
    r.z = expf(v1);
    r.w = 0.f;
    csr[pos] = r;
}

// ------- per-node aggregation (bf16 h gather, 4x unrolled) + fused fc1 -------
__global__ __launch_bounds__(256) void k_node_aggregate(const float4* __restrict__ csr,
                                                        const int* __restrict__ offs,
                                                        const int* __restrict__ deg,
                                                        const unsigned short* __restrict__ hb,
                                                        const float* __restrict__ bias,
                                                        const float* __restrict__ fc1_w,
                                                        const float* __restrict__ fc1_b,
                                                        float* __restrict__ p_src,
                                                        float* __restrict__ p_dst) {
    __shared__ float red[4][6];
    const int n = blockIdx.x;
    const int t = threadIdx.x;
    const int hd = t >> 7;
    const int s = offs[n];
    const int e = s + deg[n];
    float acc0 = 0.f, acc1 = 0.f, acc2 = 0.f, acc3 = 0.f;
    float zs0 = 0.f, zs1 = 0.f;
    int it = s;
    for (; it + 4 <= e; it += 4) {
        float4 r0 = csr[it], r1 = csr[it + 1], r2 = csr[it + 2], r3 = csr[it + 3];
        int s0 = __float_as_int(r0.x), s1 = __float_as_int(r1.x);
        int s2 = __float_as_int(r2.x), s3 = __float_as_int(r3.x);
        float w0 = hd ? r0.z : r0.y;
        float w1 = hd ? r1.z : r1.y;
        float w2 = hd ? r2.z : r2.y;
        float w3 = hd ? r3.z : r3.y;
        acc0 += w0 * bf2f(hb[s0 * FDIM + t]);
        acc1 += w1 * bf2f(hb[s1 * FDIM + t]);
        acc2 += w2 * bf2f(hb[s2 * FDIM + t]);
        acc3 += w3 * bf2f(hb[s3 * FDIM + t]);
        zs0 += w0 + w1;
        zs1 += w2 + w3;
    }
    for (; it < e; ++it) {
        float4 r = csr[it];
        int sr = __float_as_int(r.x);
        float w = hd ? r.z : r.y;
        acc0 += w * bf2f(hb[sr * FDIM + t]);
        zs0 += w;
    }
    float acc = (acc0 + acc1) + (acc2 + acc3);
    float zs  = zs0 + zs1;
    float h2 = acc / zs + bias[t];
    h2 = h2 > 0.f ? h2 : 0.01f * h2;
    // 6 dots: p_src[k] = sum_t fc1_w[k*512+t]*h2 ; p_dst[k] = sum_t fc1_w[k*512+256+t]*h2
    float v0 = fc1_w[0 * 512 + t] * h2;
    float v1 = fc1_w[1 * 512 + t] * h2;
    float v2 = fc1_w[2 * 512 + t] * h2;
    float v3 = fc1_w[0 * 512 + 256 + t] * h2;
    float v4 = fc1_w[1 * 512 + 256 + t] * h2;
    float v5 = fc1_w[2 * 512 + 256 + t] * h2;
    #pragma unroll
    for (int o = 32; o > 0; o >>= 1) {
        v0 += __shfl_down(v0, o); v1 += __shfl_down(v1, o); v2 += __shfl_down(v2, o);
        v3 += __shfl_down(v3, o); v4 += __shfl_down(v4, o); v5 += __shfl_down(v5, o);
    }
    int lane = t & 63, w = t >> 6;
    if (lane == 0) {
        red[w][0] = v0; red[w][1] = v1; red[w][2] = v2;
        red[w][3] = v3; red[w][4] = v4; red[w][5] = v5;
    }
    __syncthreads();
    if (t < 6) {
        float sum = red[0][t] + red[1][t] + red[2][t] + red[3][t];
        if (t < 3) p_src[n * 4 + t] = sum + fc1_b[t];       // float4-padded, bias folded
        else       p_dst[n * 4 + (t - 3)] = sum;
    }
}

// ---------------- final per-edge output ----------------
__global__ void k_edge_out(const int* __restrict__ ei,
                           const float* __restrict__ p_src,
                           const float* __restrict__ p_dst,
                           float* __restrict__ out) {
    int i = blockIdx.x * 256 + threadIdx.x;
    if (i >= N_EDGES) return;
    int s = ei[i], d = ei[N_EDGES + i];
    f32x4 ps = *reinterpret_cast<const f32x4*>(p_src + s * 4);
    f32x4 pd = *reinterpret_cast<const f32x4*>(p_dst + d * 4);
    out[i * 3 + 0] = ps.x + pd.x;
    out[i * 3 + 1] = ps.y + pd.y;
    out[i * 3 + 2] = ps.z + pd.z;
}

extern "C" void kernel_launch(void* const* d_in, const int* in_sizes, int n_in,
                              void* d_out, int out_size, void* d_ws, size_t ws_size,
                              hipStream_t stream) {
    const float* x       = (const float*)d_in[0];
    const int*   ei      = (const int*)d_in[1];
    const float* W       = (const float*)d_in[2];
    const float* att_src = (const float*)d_in[3];
    const float* att_dst = (const float*)d_in[4];
    const float* bias    = (const float*)d_in[5];
    const float* fc1_w   = (const float*)d_in[6];
    const float* fc1_b   = (const float*)d_in[7];
    float* out = (float*)d_out;

    // workspace layout (all 16B-aligned)
    float4* csr = (float4*)d_ws;                             // 275000*16 = 4,400,000 B
    unsigned short* hb = (unsigned short*)(csr + N_TOT);     // M_PAD*256*2 = 12,812,288 B
    float* a_src = (float*)(hb + M_PAD * FDIM);              // 50000*4
    float* a_dst = a_src + 2 * N_NODES;                      // 50000*4
    float* p_src = a_dst + 2 * N_NODES;                      // 100000*4 (float4-padded)
    float* p_dst = p_src + 4 * N_NODES;                      // 100000*4
    int* deg     = (int*)(p_dst + 4 * N_NODES);              // 25000*4
    int* offs    = deg + N_NODES;
    int* cursor  = offs + N_NODES;
    int* bsum    = cursor + N_NODES;                         // 128

    k_init<<<NB_SCAN, 256, 0, stream>>>(deg);
    k_deg<<<(N_EDGES + 255) / 256, 256, 0, stream>>>(ei, deg);
    k_gemm<<<(M_PAD / 64), 512, 0, stream>>>(x, W, hb);
    k_att<<<(N_NODES + 3) / 4, 256, 0, stream>>>(hb, att_src, att_dst, a_src, a_dst);
    k_scan1<<<NB_SCAN, 256, 0, stream>>>(deg, offs, bsum);
    k_scan2<<<1, 128, 0, stream>>>(bsum);
    k_scan3<<<NB_SCAN, 256, 0, stream>>>(offs, bsum, cursor);
    k_csr_fill<<<(N_TOT + 255) / 256, 256, 0, stream>>>(ei, a_src, a_dst, cursor, csr);
    k_node_aggregate<<<N_NODES, 256, 0, stream>>>(csr, offs, deg, hb, bias, fc1_w, fc1_b,
                                                  p_src, p_dst);
    k_edge_out<<<(N_EDGES + 255) / 256, 256, 0, stream>>>(ei, p_src, p_dst, out);
}

// Round 4
// 165.689 us; speedup vs baseline: 1.7963x; 1.1571x over previous
//
#include <hip/hip_runtime.h>
#include <hip/hip_bf16.h>

#define N_NODES 25000
#define N_EDGES 250000
#define N_TOT   275000   // edges + self loops
#define FDIM    256      // HEADS*HID
#define NB_SCAN 98       // ceil(N_NODES/256)
#define M_PAD   25024    // 391*64 (gemm row padding)

typedef __attribute__((ext_vector_type(8))) short bf16x8;
typedef __attribute__((ext_vector_type(4))) float f32x4;

__device__ inline float bf2f(unsigned short s) {
    union { unsigned u; float f; } v; v.u = ((unsigned)s) << 16;
    return v.f;
}

// ---------------- degree count (edges only; self loop via +1 in scan) --------
__global__ void k_deg(const int* __restrict__ ei, int* __restrict__ deg) {
    int i = blockIdx.x * 256 + threadIdx.x;
    if (i < N_EDGES) atomicAdd(&deg[ei[N_EDGES + i]], 1);
}

// ------- MFMA GEMM + fused attention dots ------------------------------------
// BM=64, BN=256 (full), BK=64. 512 threads = 8 waves, wave = 32 rows x 64 cols.
// LDS tiles [row][64k] bf16 with XOR swizzle byte^=(row&7)<<4 (T2).
__global__ __launch_bounds__(512) void k_gemm(const float* __restrict__ x,
                                              const float* __restrict__ W,
                                              const float* __restrict__ att_src,
                                              const float* __restrict__ att_dst,
                                              __hip_bfloat16* __restrict__ hb,
                                              float* __restrict__ a_src,
                                              float* __restrict__ a_dst) {
    __shared__ char lds[40960];          // A: [0,8K) 64x64, B: [8K,40K) 256x64
    __shared__ float s_as[64][2];        // per-row per-head attention partials
    __shared__ float s_ad[64][2];
    const int m0   = blockIdx.x * 64;
    const int t    = threadIdx.x;
    const int lane = t & 63;
    const int wid  = t >> 6;             // 0..7
    const int wr   = wid >> 2;           // row-group (32 rows)
    const int wc   = wid & 3;            // col-group (64 cols)
    if (t < 256) {
        s_as[t >> 2][t & 1] = 0.f;       // covers [64][2] twice; cheap+safe
        s_ad[t >> 2][t & 1] = 0.f;
    }
    f32x4 acc[2][4];
    #pragma unroll
    for (int mi = 0; mi < 2; ++mi)
        #pragma unroll
        for (int ni = 0; ni < 4; ++ni)
            acc[mi][ni] = (f32x4){0.f, 0.f, 0.f, 0.f};

    for (int kc = 0; kc < 256; kc += 64) {
        __syncthreads();                 // protect LDS reuse
        // stage A: 64 rows x 64 k  (1024 float4, 2 per thread)
        #pragma unroll
        for (int q = 0; q < 2; ++q) {
            int fi = q * 512 + t;
            int row = fi >> 4, ks4 = fi & 15;
            int node = m0 + row;
            f32x4 v = (f32x4){0.f, 0.f, 0.f, 0.f};
            if (node < N_NODES) v = *reinterpret_cast<const f32x4*>(x + node * 256 + kc + ks4 * 4);
            __hip_bfloat16 b[4];
            b[0] = __float2bfloat16(v.x); b[1] = __float2bfloat16(v.y);
            b[2] = __float2bfloat16(v.z); b[3] = __float2bfloat16(v.w);
            int byte = (row * 128 + ks4 * 8) ^ ((row & 7) << 4);
            *reinterpret_cast<ushort4*>(lds + byte) = *reinterpret_cast<const ushort4*>(b);
        }
        // stage B: 256 cols x 64 k (4096 float4, 8 per thread)
        #pragma unroll
        for (int q = 0; q < 8; ++q) {
            int fi = q * 512 + t;
            int col = fi >> 4, ks4 = fi & 15;
            f32x4 v = *reinterpret_cast<const f32x4*>(W + col * 256 + kc + ks4 * 4);
            __hip_bfloat16 b[4];
            b[0] = __float2bfloat16(v.x); b[1] = __float2bfloat16(v.y);
            b[2] = __float2bfloat16(v.z); b[3] = __float2bfloat16(v.w);
            int byte = 8192 + ((col * 128 + ks4 * 8) ^ ((col & 7) << 4));
            *reinterpret_cast<ushort4*>(lds + byte) = *reinterpret_cast<const ushort4*>(b);
        }
        __syncthreads();
        #pragma unroll
        for (int ks = 0; ks < 2; ++ks) {
            bf16x8 a[2], b[4];
            #pragma unroll
            for (int mi = 0; mi < 2; ++mi) {
                int row = wr * 32 + mi * 16 + (lane & 15);
                int byte = (row * 128 + ks * 64 + (lane >> 4) * 16) ^ ((row & 7) << 4);
                a[mi] = *reinterpret_cast<const bf16x8*>(lds + byte);
            }
            #pragma unroll
            for (int ni = 0; ni < 4; ++ni) {
                int col = wc * 64 + ni * 16 + (lane & 15);
                int byte = 8192 + ((col * 128 + ks * 64 + (lane >> 4) * 16) ^ ((col & 7) << 4));
                b[ni] = *reinterpret_cast<const bf16x8*>(lds + byte);
            }
            #pragma unroll
            for (int mi = 0; mi < 2; ++mi)
                #pragma unroll
                for (int ni = 0; ni < 4; ++ni)
                    acc[mi][ni] = __builtin_amdgcn_mfma_f32_16x16x32_bf16(
                        a[mi], b[ni], acc[mi][ni], 0, 0, 0);
        }
    }
    // epilogue 1: store bf16 h. C/D layout col = lane&15, row = (lane>>4)*4 + r
    #pragma unroll
    for (int mi = 0; mi < 2; ++mi)
        #pragma unroll
        for (int r = 0; r < 4; ++r) {
            int row = m0 + wr * 32 + mi * 16 + (lane >> 4) * 4 + r;   // < M_PAD (hb padded)
            #pragma unroll
            for (int ni = 0; ni < 4; ++ni) {
                int col = wc * 64 + ni * 16 + (lane & 15);
                hb[row * 256 + col] = __float2bfloat16(acc[mi][ni][r]);
            }
        }
    // epilogue 2: fused attention partial dots (f32 accs), LDS accumulate
    const int hd0 = wc >> 1;
    float as_[4], ad_[4];
    #pragma unroll
    for (int ni = 0; ni < 4; ++ni) {
        int col = wc * 64 + ni * 16 + (lane & 15);
        as_[ni] = att_src[col];
        ad_[ni] = att_dst[col];
    }
    #pragma unroll
    for (int mi = 0; mi < 2; ++mi)
        #pragma unroll
        for (int r = 0; r < 4; ++r) {
            float ps = acc[mi][0][r] * as_[0] + acc[mi][1][r] * as_[1]
                     + acc[mi][2][r] * as_[2] + acc[mi][3][r] * as_[3];
            float pd = acc[mi][0][r] * ad_[0] + acc[mi][1][r] * ad_[1]
                     + acc[mi][2][r] * ad_[2] + acc[mi][3][r] * ad_[3];
            #pragma unroll
            for (int o = 8; o > 0; o >>= 1) {   // reduce over lane&15 groups
                ps += __shfl_down(ps, o);
                pd += __shfl_down(pd, o);
            }
            if ((lane & 15) == 0) {
                int rl = wr * 32 + mi * 16 + (lane >> 4) * 4 + r;   // 0..63
                atomicAdd(&s_as[rl][hd0], ps);
                atomicAdd(&s_ad[rl][hd0], pd);
            }
        }
    __syncthreads();
    if (t < 128) {
        int rl = t >> 1, hd = t & 1;
        int row = m0 + rl;
        if (row < N_NODES) {
            a_src[row * 2 + hd] = s_as[rl][hd];
            a_dst[row * 2 + hd] = s_ad[rl][hd];
        }
    }
}

// ---------------- hierarchical exclusive scan of (deg+1) -> offs -------------
__global__ __launch_bounds__(256) void k_scan1(const int* __restrict__ deg,
                                               int* __restrict__ offs,
                                               int* __restrict__ bsum) {
    __shared__ int sh[256];
    int b = blockIdx.x, t = threadIdx.x;
    int i = b * 256 + t;
    int v = (i < N_NODES) ? (deg[i] + 1) : 0;   // +1 = self loop
    sh[t] = v;
    __syncthreads();
    #pragma unroll
    for (int o = 1; o < 256; o <<= 1) {
        int u = (t >= o) ? sh[t - o] : 0;
        __syncthreads();
        sh[t] += u;
        __syncthreads();
    }
    int incl = sh[t];
    if (i < N_NODES) offs[i] = incl - v;
    if (t == 255) bsum[b] = incl;
}

__global__ __launch_bounds__(128) void k_scan2(int* __restrict__ bsum) {
    __shared__ int sh[128];
    int t = threadIdx.x;
    int v = (t < NB_SCAN) ? bsum[t] : 0;
    sh[t] = v;
    __syncthreads();
    #pragma unroll
    for (int o = 1; o < 128; o <<= 1) {
        int u = (t >= o) ? sh[t - o] : 0;
        __syncthreads();
        sh[t] += u;
        __syncthreads();
    }
    if (t < NB_SCAN) bsum[t] = sh[t] - v;   // exclusive
}

__global__ __launch_bounds__(256) void k_scan3(int* __restrict__ offs,
                                               const int* __restrict__ bsum,
                                               int* __restrict__ cursor) {
    int i = blockIdx.x * 256 + threadIdx.x;
    if (i < N_NODES) {
        int o = offs[i] + bsum[i >> 8];
        offs[i]   = o;
        cursor[i] = o;
    }
}

// ------- CSR fill: compute ex inline, scatter {src, ex0, ex1} -------
__global__ void k_csr_fill(const int* __restrict__ ei,
                           const float* __restrict__ a_src,
                           const float* __restrict__ a_dst,
                           int* __restrict__ cursor,
                           float4* __restrict__ csr) {
    int i = blockIdx.x * 256 + threadIdx.x;
    if (i >= N_TOT) return;
    int src, dst;
    if (i < N_EDGES) { src = ei[i]; dst = ei[N_EDGES + i]; }
    else             { src = dst = i - N_EDGES; }
    float2 as = *reinterpret_cast<const float2*>(a_src + src * 2);
    float2 ad = *reinterpret_cast<const float2*>(a_dst + dst * 2);
    float v0 = as.x + ad.x;
    float v1 = as.y + ad.y;
    v0 = v0 > 0.f ? v0 : 0.2f * v0;
    v1 = v1 > 0.f ? v1 : 0.2f * v1;
    int pos = atomicAdd(&cursor[dst], 1);
    float4 r;
    r.x = __int_as_float(src);
    r.y = expf(v0);          // softmax shift-invariant; |v| small -> no max pass
    r.z = expf(v1);
    r.w = 0.f;
    csr[pos] = r;
}

// ------- wave-per-node aggregation (8B/lane bf16 gather) + fused fc1 ---------
__global__ __launch_bounds__(256) void k_node_aggregate(const float4* __restrict__ csr,
                                                        const int* __restrict__ offs,
                                                        const int* __restrict__ deg,
                                                        const unsigned short* __restrict__ hb,
                                                        const float* __restrict__ bias,
                                                        const float* __restrict__ fc1_w,
                                                        const float* __restrict__ fc1_b,
                                                        float* __restrict__ p_src,
                                                        float* __restrict__ p_dst) {
    const int n = (blockIdx.x << 2) + (threadIdx.x >> 6);
    const int lane = threadIdx.x & 63;
    if (n >= N_NODES) return;
    const int s = offs[n];
    const int e = s + deg[n] + 1;          // + self loop
    f32x4 acc0 = (f32x4){0.f, 0.f, 0.f, 0.f};
    f32x4 acc1 = (f32x4){0.f, 0.f, 0.f, 0.f};
    float zs0 = 0.f, zs1 = 0.f;
    int it = s;
    for (; it + 2 <= e; it += 2) {
        float4 r0 = csr[it], r1 = csr[it + 1];
        int s0 = __float_as_int(r0.x), s1 = __float_as_int(r1.x);
        float w0 = lane < 32 ? r0.y : r0.z;
        float w1 = lane < 32 ? r1.y : r1.z;
        ushort4 h0 = *reinterpret_cast<const ushort4*>(hb + s0 * FDIM + lane * 4);
        ushort4 h1 = *reinterpret_cast<const ushort4*>(hb + s1 * FDIM + lane * 4);
        acc0.x += w0 * bf2f(h0.x); acc0.y += w0 * bf2f(h0.y);
        acc0.z += w0 * bf2f(h0.z); acc0.w += w0 * bf2f(h0.w);
        acc1.x += w1 * bf2f(h1.x); acc1.y += w1 * bf2f(h1.y);
        acc1.z += w1 * bf2f(h1.z); acc1.w += w1 * bf2f(h1.w);
        zs0 += w0; zs1 += w1;
    }
    if (it < e) {
        float4 r0 = csr[it];
        int s0 = __float_as_int(r0.x);
        float w0 = lane < 32 ? r0.y : r0.z;
        ushort4 h0 = *reinterpret_cast<const ushort4*>(hb + s0 * FDIM + lane * 4);
        acc0.x += w0 * bf2f(h0.x); acc0.y += w0 * bf2f(h0.y);
        acc0.z += w0 * bf2f(h0.z); acc0.w += w0 * bf2f(h0.w);
        zs0 += w0;
    }
    const float inv = 1.f / (zs0 + zs1);
    f32x4 bv = *reinterpret_cast<const f32x4*>(bias + lane * 4);
    float h2_0 = (acc0.x + acc1.x) * inv + bv.x;
    float h2_1 = (acc0.y + acc1.y) * inv + bv.y;
    float h2_2 = (acc0.z + acc1.z) * inv + bv.z;
    float h2_3 = (acc0.w + acc1.w) * inv + bv.w;
    h2_0 = h2_0 > 0.f ? h2_0 : 0.01f * h2_0;
    h2_1 = h2_1 > 0.f ? h2_1 : 0.01f * h2_1;
    h2_2 = h2_2 > 0.f ? h2_2 : 0.01f * h2_2;
    h2_3 = h2_3 > 0.f ? h2_3 : 0.01f * h2_3;
    // 6 dots over 256 dims (4 per lane): p_src uses fc1_w[k][0:256], p_dst [256:512]
    f32x4 wa0 = *reinterpret_cast<const f32x4*>(fc1_w + 0 * 512 + lane * 4);
    f32x4 wa1 = *reinterpret_cast<const f32x4*>(fc1_w + 1 * 512 + lane * 4);
    f32x4 wa2 = *reinterpret_cast<const f32x4*>(fc1_w + 2 * 512 + lane * 4);
    f32x4 wb0 = *reinterpret_cast<const f32x4*>(fc1_w + 0 * 512 + 256 + lane * 4);
    f32x4 wb1 = *reinterpret_cast<const f32x4*>(fc1_w + 1 * 512 + 256 + lane * 4);
    f32x4 wb2 = *reinterpret_cast<const f32x4*>(fc1_w + 2 * 512 + 256 + lane * 4);
    float v0 = wa0.x * h2_0 + wa0.y * h2_1 + wa0.z * h2_2 + wa0.w * h2_3;
    float v1 = wa1.x * h2_0 + wa1.y * h2_1 + wa1.z * h2_2 + wa1.w * h2_3;
    float v2 = wa2.x * h2_0 + wa2.y * h2_1 + wa2.z * h2_2 + wa2.w * h2_3;
    float v3 = wb0.x * h2_0 + wb0.y * h2_1 + wb0.z * h2_2 + wb0.w * h2_3;
    float v4 = wb1.x * h2_0 + wb1.y * h2_1 + wb1.z * h2_2 + wb1.w * h2_3;
    float v5 = wb2.x * h2_0 + wb2.y * h2_1 + wb2.z * h2_2 + wb2.w * h2_3;
    #pragma unroll
    for (int o = 32; o > 0; o >>= 1) {
        v0 += __shfl_down(v0, o); v1 += __shfl_down(v1, o); v2 += __shfl_down(v2, o);
        v3 += __shfl_down(v3, o); v4 += __shfl_down(v4, o); v5 += __shfl_down(v5, o);
    }
    if (lane == 0) {
        f32x4 ps = (f32x4){v0 + fc1_b[0], v1 + fc1_b[1], v2 + fc1_b[2], 0.f};
        f32x4 pd = (f32x4){v3, v4, v5, 0.f};
        *reinterpret_cast<f32x4*>(p_src + n * 4) = ps;
        *reinterpret_cast<f32x4*>(p_dst + n * 4) = pd;
    }
}

// ---------------- final per-edge output ----------------
__global__ void k_edge_out(const int* __restrict__ ei,
                           const float* __restrict__ p_src,
                           const float* __restrict__ p_dst,
                           float* __restrict__ out) {
    int i = blockIdx.x * 256 + threadIdx.x;
    if (i >= N_EDGES) return;
    int s = ei[i], d = ei[N_EDGES + i];
    f32x4 ps = *reinterpret_cast<const f32x4*>(p_src + s * 4);
    f32x4 pd = *reinterpret_cast<const f32x4*>(p_dst + d * 4);
    out[i * 3 + 0] = ps.x + pd.x;
    out[i * 3 + 1] = ps.y + pd.y;
    out[i * 3 + 2] = ps.z + pd.z;
}

extern "C" void kernel_launch(void* const* d_in, const int* in_sizes, int n_in,
                              void* d_out, int out_size, void* d_ws, size_t ws_size,
                              hipStream_t stream) {
    const float* x       = (const float*)d_in[0];
    const int*   ei      = (const int*)d_in[1];
    const float* W       = (const float*)d_in[2];
    const float* att_src = (const float*)d_in[3];
    const float* att_dst = (const float*)d_in[4];
    const float* bias    = (const float*)d_in[5];
    const float* fc1_w   = (const float*)d_in[6];
    const float* fc1_b   = (const float*)d_in[7];
    float* out = (float*)d_out;

    // workspace layout (all 16B-aligned)
    float4* csr = (float4*)d_ws;                             // 275000*16 B
    __hip_bfloat16* hb = (__hip_bfloat16*)(csr + N_TOT);     // M_PAD*256 bf16
    float* a_src = (float*)(hb + M_PAD * FDIM);              // 50000
    float* a_dst = a_src + 2 * N_NODES;                      // 50000
    float* p_src = a_dst + 2 * N_NODES;                      // 100000 (float4-padded)
    float* p_dst = p_src + 4 * N_NODES;                      // 100000
    int* deg     = (int*)(p_dst + 4 * N_NODES);              // 25000
    int* offs    = deg + N_NODES;
    int* cursor  = offs + N_NODES;
    int* bsum    = cursor + N_NODES;                         // 128

    hipMemsetAsync(deg, 0, N_NODES * sizeof(int), stream);
    k_deg<<<(N_EDGES + 255) / 256, 256, 0, stream>>>(ei, deg);
    k_gemm<<<(M_PAD / 64), 512, 0, stream>>>(x, W, att_src, att_dst, hb, a_src, a_dst);
    k_scan1<<<NB_SCAN, 256, 0, stream>>>(deg, offs, bsum);
    k_scan2<<<1, 128, 0, stream>>>(bsum);
    k_scan3<<<NB_SCAN, 256, 0, stream>>>(offs, bsum, cursor);
    k_csr_fill<<<(N_TOT + 255) / 256, 256, 0, stream>>>(ei, a_src, a_dst, cursor, csr);
    k_node_aggregate<<<(N_NODES + 3) / 4, 256, 0, stream>>>(
        csr, offs, deg, (const unsigned short*)hb, bias, fc1_w, fc1_b, p_src, p_dst);
    k_edge_out<<<(N_EDGES + 255) / 256, 256, 0, stream>>>(ei, p_src, p_dst, out);
}